// Round 1
// baseline (156.538 us; speedup 1.0000x reference)
//
#include <hip/hip_runtime.h>
#include <stdint.h>

// YatConv: y = scale * (dot^2 / (||patch||^2 - 2*dot + ||W_o||^2 + eps) + bias)
// x: [16][64][64][128] f32, kernel: [3][3][128][256] f32 (HWIO), out: [16][64][64][256] f32
// Implicit GEMM: M=65536 pixels, N=256 out-channels, K=1152, bf16 MFMA.

#define NB 16
#define HH 64
#define WW 64
#define CC 128
#define OO 256
#define HP 66
#define WP 66
#define KTOT 1152
#define EPSV 1e-5f

typedef short short8 __attribute__((ext_vector_type(8)));
typedef float f32x4 __attribute__((ext_vector_type(4)));

__device__ __forceinline__ unsigned short f2bf(float f) {
  unsigned u = __builtin_bit_cast(unsigned, f);
  u += 0x7fffu + ((u >> 16) & 1u);   // round-to-nearest-even
  return (unsigned short)(u >> 16);
}

__device__ __forceinline__ void gload_lds16(const void* g, void* l) {
  __builtin_amdgcn_global_load_lds(
      (const __attribute__((address_space(1))) unsigned int*)g,
      (__attribute__((address_space(3))) unsigned int*)l,
      16, 0, 0);
}

// ---- prep 1: x (f32) -> padded bf16 [16][66][66][128] with zero halo, plus
//              s2p[b][hp][wp] = sum_c x^2 (f32, zero halo). One wave per padded pixel.
__global__ __launch_bounds__(256) void prep_x(const float* __restrict__ x,
                                              unsigned short* __restrict__ xp,
                                              float* __restrict__ s2p) {
  int gw = (blockIdx.x << 2) + (threadIdx.x >> 6);   // padded pixel index
  int lane = threadIdx.x & 63;
  int b = gw / (HP * WP);
  int rem = gw - b * (HP * WP);
  int hp = rem / WP;
  int wp = rem - hp * WP;
  float2 v = make_float2(0.f, 0.f);
  if (hp >= 1 && hp <= HH && wp >= 1 && wp <= WW) {
    const float2* src = (const float2*)(x + (size_t)(((b * HH) + hp - 1) * WW + (wp - 1)) * CC);
    v = src[lane];
  }
  ushort2 o2;
  o2.x = f2bf(v.x);
  o2.y = f2bf(v.y);
  ((ushort2*)(xp + (size_t)gw * CC))[lane] = o2;
  float ss = v.x * v.x + v.y * v.y;
  #pragma unroll
  for (int off = 32; off > 0; off >>= 1) ss += __shfl_down(ss, off);
  if (lane == 0) s2p[gw] = ss;
}

// ---- prep 2: kernel [1152][256] f32 -> Wt [256][1152] bf16 (B^T layout),
//              ksq[o] = sum_k W^2 (f32). One block per output channel.
__global__ __launch_bounds__(256) void prep_w(const float* __restrict__ kern,
                                              unsigned short* __restrict__ wt,
                                              float* __restrict__ ksq) {
  int o = blockIdx.x;
  int t = threadIdx.x;
  float acc = 0.f;
  for (int k = t; k < KTOT; k += 256) {
    float v = kern[(size_t)k * OO + o];
    wt[(size_t)o * KTOT + k] = f2bf(v);
    acc += v * v;
  }
  __shared__ float red[256];
  red[t] = acc;
  __syncthreads();
  #pragma unroll
  for (int s = 128; s > 0; s >>= 1) {
    if (t < s) red[t] += red[t + s];
    __syncthreads();
  }
  if (t == 0) ksq[o] = red[0];
}

// ---- main: implicit-GEMM conv, 128x128 tile, BK=32, 4 waves, m97 structure.
__global__ __launch_bounds__(256) void yat_main(
    const unsigned short* __restrict__ xp,
    const unsigned short* __restrict__ wt,
    const float* __restrict__ s2p,
    const float* __restrict__ ksq,
    const float* __restrict__ bias,
    const float* __restrict__ alpha,
    float* __restrict__ out) {
  __shared__ unsigned short As[128 * 32];   // [row pixel][k] 8 KiB
  __shared__ unsigned short Bs[128 * 32];   // [out ch][k]   8 KiB
  __shared__ float ps[128];                 // patch ||x||^2 per tile pixel

  int bid = blockIdx.x;
  // bijective XCD swizzle: 1024 = 8 * 128
  int swz = ((bid & 7) << 7) + (bid >> 3);
  int mt = swz >> 1;
  int nt = swz & 1;           // N-tile innermost: both share A panel in L2
  int m0 = mt << 7;
  int n0 = nt << 7;

  int tid = threadIdx.x;
  int wid = tid >> 6;
  int lane = tid & 63;

  // staging: wave covers 16 rows x 32 k per 1 KiB chunk; lane -> (row=l>>2, k8=(l&3)*8)
  int r0 = (wid << 4) + (lane >> 2);
  int csub = (lane & 3) << 3;

  const unsigned short* aSrc0;
  const unsigned short* aSrc1;
  {
    int p = m0 + r0;
    int b = p >> 12, hw = p & 4095;
    int h = hw >> 6, w = hw & 63;
    aSrc0 = xp + (size_t)((b * HP + h + 1) * WP + (w + 1)) * CC + csub;
    p = m0 + 64 + r0;
    b = p >> 12; hw = p & 4095; h = hw >> 6; w = hw & 63;
    aSrc1 = xp + (size_t)((b * HP + h + 1) * WP + (w + 1)) * CC + csub;
  }
  const unsigned short* bSrc0 = wt + (size_t)(n0 + r0) * KTOT + csub;
  const unsigned short* bSrc1 = wt + (size_t)(n0 + 64 + r0) * KTOT + csub;

  unsigned short* aDst0 = As + (wid << 9);           // bytes: wid*1024
  unsigned short* aDst1 = As + 2048 + (wid << 9);
  unsigned short* bDst0 = Bs + (wid << 9);
  unsigned short* bDst1 = Bs + 2048 + (wid << 9);

  int wr = wid >> 1;                                  // wave 64x64 quadrant
  int wc = wid & 1;
  int aOff = ((wr << 6) + (lane & 15)) * 64 + ((lane >> 4) << 4);  // bytes
  int bOff = ((wc << 6) + (lane & 15)) * 64 + ((lane >> 4) << 4);

  f32x4 acc[4][4] = {};

  #pragma unroll
  for (int dy = 0; dy < 3; ++dy) {
    #pragma unroll
    for (int dx = 0; dx < 3; ++dx) {
      const int aTap = (dy * WP + dx - (WP + 1)) * CC;  // halo-padded shift
      const int bTap = (dy * 3 + dx) * CC;
      #pragma unroll
      for (int c4 = 0; c4 < 4; ++c4) {
        const int coff = c4 << 5;
        __syncthreads();
        gload_lds16(aSrc0 + aTap + coff, aDst0);
        gload_lds16(aSrc1 + aTap + coff, aDst1);
        gload_lds16(bSrc0 + bTap + coff, bDst0);
        gload_lds16(bSrc1 + bTap + coff, bDst1);
        __syncthreads();
        short8 af[4], bf[4];
        #pragma unroll
        for (int m = 0; m < 4; ++m)
          af[m] = *(const short8*)((const char*)As + aOff + (m << 10));
        #pragma unroll
        for (int n = 0; n < 4; ++n)
          bf[n] = *(const short8*)((const char*)Bs + bOff + (n << 10));
        #pragma unroll
        for (int m = 0; m < 4; ++m) {
          #pragma unroll
          for (int n = 0; n < 4; ++n)
            acc[m][n] = __builtin_amdgcn_mfma_f32_16x16x32_bf16(af[m], bf[n], acc[m][n], 0, 0, 0);
        }
      }
    }
  }

  // ---- epilogue ----
  __syncthreads();
  if (tid < 128) {
    int p = m0 + tid;
    int b = p >> 12, hw = p & 4095;
    int h = hw >> 6, w = hw & 63;
    const float* s2 = s2p + (b * HP + h) * WP + w;    // top-left of 3x3 in padded coords
    float s = 0.f;
    #pragma unroll
    for (int dy = 0; dy < 3; ++dy) {
      #pragma unroll
      for (int dx = 0; dx < 3; ++dx) s += s2[dy * WP + dx];
    }
    ps[tid] = s;
  }
  __syncthreads();

  float al = alpha[0];
  float scale = powf(16.0f / logf(257.0f), al);   // (sqrt(256)/log1p(256))^alpha

  int c0 = n0 + (wc << 6) + (lane & 15);
  int rb = (wr << 6) + ((lane >> 4) << 2);
  #pragma unroll
  for (int n = 0; n < 4; ++n) {
    int cn = c0 + (n << 4);
    float kq = ksq[cn] + EPSV;
    float bv = bias[cn];
    #pragma unroll
    for (int m = 0; m < 4; ++m) {
      f32x4 a = acc[m][n];
      #pragma unroll
      for (int j = 0; j < 4; ++j) {
        int rm = rb + (m << 4) + j;
        float dot = a[j];
        float dist = ps[rm] - 2.0f * dot + kq;      // +eps folded into kq
        float y = dot * dot / dist + bv;
        out[(size_t)(m0 + rm) * OO + cn] = y * scale;
      }
    }
  }
}

extern "C" void kernel_launch(void* const* d_in, const int* in_sizes, int n_in,
                              void* d_out, int out_size, void* d_ws, size_t ws_size,
                              hipStream_t stream) {
  const float* x = (const float*)d_in[0];
  const float* kern = (const float*)d_in[1];
  const float* bias = (const float*)d_in[2];
  const float* alpha = (const float*)d_in[3];
  float* out = (float*)d_out;

  char* ws = (char*)d_ws;
  unsigned short* xp  = (unsigned short*)ws;                 // 16*66*66*128*2 = 17,842,176 B
  unsigned short* wtb = (unsigned short*)(ws + 17842176);    // 256*1152*2    =    589,824 B
  float* s2p = (float*)(ws + 18432000);                      // 16*66*66*4    =    278,784 B
  float* ksq = (float*)(ws + 18710784);                      // 256*4         =      1,024 B

  prep_x<<<17424, 256, 0, stream>>>(x, xp, s2p);             // 69696 padded pixels / 4 waves
  prep_w<<<256, 256, 0, stream>>>(kern, wtb, ksq);
  yat_main<<<1024, 256, 0, stream>>>(xp, wtb, s2p, ksq, bias, alpha, out);
}

// Round 3
// 149.903 us; speedup vs baseline: 1.0443x; 1.0443x over previous
//
#include <hip/hip_runtime.h>
#include <stdint.h>

// YatConv: y = scale * (dot^2 / (||patch||^2 - 2*dot + ||W_o||^2 + eps) + bias)
// x: [16][64][64][128] f32, kernel: [3][3][128][256] f32 (HWIO), out: [16][64][64][256] f32
// Implicit GEMM: M=65536 pixels, N=256 out-channels, K=1152, bf16 MFMA.
// v2b: 256x128 tile, BK=64, 8 waves, ring-3 LDS, counted vmcnt (T3/T4), XOR swizzle (T2),
//      setprio (T5). v2->v2b: unconditional hipFuncSetAttribute (harness contract).

#define HH 64
#define WW 64
#define CC 128
#define OO 256
#define HP 66
#define WP 66
#define KTOT 1152
#define NKT 18
#define EPSV 1e-5f

#define BM 256
#define BN 128
#define SLOT_BYTES 49152   // A 32KB + B 16KB per K-tile buffer
#define B_OFF 32768
#define SMEM_TOTAL (3 * SLOT_BYTES + 1024)

typedef short short8 __attribute__((ext_vector_type(8)));
typedef float f32x4 __attribute__((ext_vector_type(4)));

__device__ __forceinline__ unsigned short f2bf(float f) {
  unsigned u = __builtin_bit_cast(unsigned, f);
  u += 0x7fffu + ((u >> 16) & 1u);   // round-to-nearest-even
  return (unsigned short)(u >> 16);
}

__device__ __forceinline__ void gload_lds16(const void* g, void* l) {
  __builtin_amdgcn_global_load_lds(
      (const __attribute__((address_space(1))) unsigned int*)g,
      (__attribute__((address_space(3))) unsigned int*)l,
      16, 0, 0);
}

#define FENCE() asm volatile("" ::: "memory")
#define BAR() do { FENCE(); __builtin_amdgcn_s_barrier(); FENCE(); } while (0)

// ---- prep 1: unchanged from round 1 (known-correct) ----
__global__ __launch_bounds__(256) void prep_x(const float* __restrict__ x,
                                              unsigned short* __restrict__ xp,
                                              float* __restrict__ s2p) {
  int gw = (blockIdx.x << 2) + (threadIdx.x >> 6);
  int lane = threadIdx.x & 63;
  int b = gw / (HP * WP);
  int rem = gw - b * (HP * WP);
  int hp = rem / WP;
  int wp = rem - hp * WP;
  float2 v = make_float2(0.f, 0.f);
  if (hp >= 1 && hp <= HH && wp >= 1 && wp <= WW) {
    const float2* src = (const float2*)(x + (size_t)(((b * HH) + hp - 1) * WW + (wp - 1)) * CC);
    v = src[lane];
  }
  ushort2 o2;
  o2.x = f2bf(v.x);
  o2.y = f2bf(v.y);
  ((ushort2*)(xp + (size_t)gw * CC))[lane] = o2;
  float ss = v.x * v.x + v.y * v.y;
  #pragma unroll
  for (int off = 32; off > 0; off >>= 1) ss += __shfl_down(ss, off);
  if (lane == 0) s2p[gw] = ss;
}

// ---- prep 2: unchanged from round 1 ----
__global__ __launch_bounds__(256) void prep_w(const float* __restrict__ kern,
                                              unsigned short* __restrict__ wt,
                                              float* __restrict__ ksq) {
  int o = blockIdx.x;
  int t = threadIdx.x;
  float acc = 0.f;
  for (int k = t; k < KTOT; k += 256) {
    float v = kern[(size_t)k * OO + o];
    wt[(size_t)o * KTOT + k] = f2bf(v);
    acc += v * v;
  }
  __shared__ float red[256];
  red[t] = acc;
  __syncthreads();
  #pragma unroll
  for (int s = 128; s > 0; s >>= 1) {
    if (t < s) red[t] += red[t + s];
    __syncthreads();
  }
  if (t == 0) ksq[o] = red[0];
}

// ---- main v2 ----
__global__ __launch_bounds__(512, 2) void yat_main(
    const unsigned short* __restrict__ xp,
    const unsigned short* __restrict__ wt,
    const float* __restrict__ s2p,
    const float* __restrict__ ksq,
    const float* __restrict__ bias,
    const float* __restrict__ alpha,
    float* __restrict__ out) {
  extern __shared__ char smem[];

  int tid = threadIdx.x;
  int wid = tid >> 6, lane = tid & 63;

  int bid = blockIdx.x;
  int swz = ((bid & 7) << 6) + (bid >> 3);   // bijective, 512 = 8*64
  int mt = swz >> 1, nt = swz & 1;           // N innermost: pairs share A panel
  int m0 = mt << 8;
  int n0 = nt << 7;

  // ---- staging source addresses (pre-swizzled: chunk cg = (tid&7) ^ ((tid>>3)&7))
  int cg = (((tid & 7) ^ ((tid >> 3) & 7)) << 3);   // half-elements
  const unsigned short* aSrc[4];
  #pragma unroll
  for (int q = 0; q < 4; ++q) {
    int r = (q << 6) + (tid >> 3);
    int p = m0 + r;
    int b = p >> 12, h = (p >> 6) & 63, w = p & 63;
    aSrc[q] = xp + (size_t)((b * HP + h) * WP + w) * CC + cg;
  }
  const unsigned short* bSrc[2];
  #pragma unroll
  for (int q = 0; q < 2; ++q) {
    int r = (q << 6) + (tid >> 3);
    bSrc[q] = wt + (size_t)(n0 + r) * KTOT + cg;
  }

  auto STAGE = [&](int t, int soff) {
    int tap = t >> 1;
    int dy = tap / 3;
    int dx = tap - dy * 3;
    int koff = (dy * WP + dx) * CC + ((t & 1) << 6);   // halfs
    char* da = smem + soff + (wid << 10);              // wave-uniform; HW adds lane*16
    #pragma unroll
    for (int q = 0; q < 4; ++q)
      gload_lds16(aSrc[q] + koff, da + (q << 13));
    int kb = t << 6;
    char* db = smem + soff + B_OFF + (wid << 10);
    #pragma unroll
    for (int q = 0; q < 2; ++q)
      gload_lds16(bSrc[q] + kb, db + (q << 13));
  };

  // ---- fragment read offsets (swizzled: chunk' = chunk ^ (row&7), row&7 == lane&7)
  int wr = wid >> 1, wcn = wid & 1;
  int rA0 = (wr << 6) + (lane & 15);
  int rB0 = (wcn << 6) + (lane & 15);
  int xsw = lane & 7;
  int co0 = (((lane >> 4) ^ xsw) << 4);          // ks=0 chunk byte offset
  int co1 = ((((lane >> 4) + 4) ^ xsw) << 4);    // ks=1

  f32x4 acc[4][4] = {};

  STAGE(0, 0);
  STAGE(1, SLOT_BYTES);

  int soff = 0;
  int stoff = 2 * SLOT_BYTES;
  for (int i = 0; i < NKT; ++i) {
    if (i < NKT - 2) STAGE(i + 2, stoff);
    // counted wait: tile i's 6 loads are the oldest outstanding
    if (i < NKT - 2)      asm volatile("s_waitcnt vmcnt(12)" ::: "memory");
    else if (i == NKT - 2) asm volatile("s_waitcnt vmcnt(6)" ::: "memory");
    else                   asm volatile("s_waitcnt vmcnt(0)" ::: "memory");
    BAR();   // all waves' tile-i loads landed

    const char* Ab = smem + soff;
    const char* Bb = Ab + B_OFF;
    short8 af[2][4], bf[2][4];
    #pragma unroll
    for (int ks = 0; ks < 2; ++ks) {
      int co = ks ? co1 : co0;
      #pragma unroll
      for (int m = 0; m < 4; ++m)
        af[ks][m] = *(const short8*)(Ab + ((rA0 + (m << 4)) << 7) + co);
      #pragma unroll
      for (int n = 0; n < 4; ++n)
        bf[ks][n] = *(const short8*)(Bb + ((rB0 + (n << 4)) << 7) + co);
    }
    asm volatile("s_waitcnt lgkmcnt(0)" ::: "memory");
    BAR();   // all waves done reading slot i -> next iter may stage over it

    __builtin_amdgcn_s_setprio(1);
    #pragma unroll
    for (int ks = 0; ks < 2; ++ks) {
      #pragma unroll
      for (int m = 0; m < 4; ++m) {
        #pragma unroll
        for (int n = 0; n < 4; ++n)
          acc[m][n] = __builtin_amdgcn_mfma_f32_16x16x32_bf16(af[ks][m], bf[ks][n], acc[m][n], 0, 0, 0);
      }
    }
    __builtin_amdgcn_s_setprio(0);

    soff += SLOT_BYTES;  if (soff == 3 * SLOT_BYTES) soff = 0;
    stoff += SLOT_BYTES; if (stoff == 3 * SLOT_BYTES) stoff = 0;
  }

  // ---- epilogue ----
  float* ps = (float*)(smem + 3 * SLOT_BYTES);
  if (tid < BM) {
    int p = m0 + tid;
    int b = p >> 12, h = (p >> 6) & 63, w = p & 63;
    const float* s2 = s2p + (b * HP + h) * WP + w;   // top-left of 3x3 in padded coords
    float s = 0.f;
    #pragma unroll
    for (int dy = 0; dy < 3; ++dy) {
      #pragma unroll
      for (int dx = 0; dx < 3; ++dx) s += s2[dy * WP + dx];
    }
    ps[tid] = s;
  }
  asm volatile("s_waitcnt lgkmcnt(0)" ::: "memory");
  BAR();

  float al = alpha[0];
  float scale = powf(16.0f / logf(257.0f), al);   // (sqrt(256)/log1p(256))^alpha

  int c0 = n0 + (wcn << 6) + (lane & 15);
  int rb = (wr << 6) + ((lane >> 4) << 2);
  #pragma unroll
  for (int n = 0; n < 4; ++n) {
    int cn = c0 + (n << 4);
    float kq = ksq[cn] + EPSV;
    float bv = bias[cn];
    #pragma unroll
    for (int m = 0; m < 4; ++m) {
      f32x4 a = acc[m][n];
      #pragma unroll
      for (int j = 0; j < 4; ++j) {
        int rm = rb + (m << 4) + j;
        float dot = a[j];
        float dist = ps[rm] - 2.0f * dot + kq;
        float y = dot * dot / dist + bv;
        out[(size_t)(m0 + rm) * OO + cn] = y * scale;
      }
    }
  }
}

extern "C" void kernel_launch(void* const* d_in, const int* in_sizes, int n_in,
                              void* d_out, int out_size, void* d_ws, size_t ws_size,
                              hipStream_t stream) {
  const float* x = (const float*)d_in[0];
  const float* kern = (const float*)d_in[1];
  const float* bias = (const float*)d_in[2];
  const float* alpha = (const float*)d_in[3];
  float* out = (float*)d_out;

  char* ws = (char*)d_ws;
  unsigned short* xp  = (unsigned short*)ws;                 // 16*66*66*128*2 = 17,842,176 B
  unsigned short* wtb = (unsigned short*)(ws + 17842176);    // 256*1152*2    =    589,824 B
  float* s2p = (float*)(ws + 18432000);                      // 16*66*66*4    =    278,784 B
  float* ksq = (float*)(ws + 18710784);                      // 256*4         =      1,024 B

  // unconditional (no static guards per harness contract); host-side, capture-safe
  (void)hipFuncSetAttribute((const void*)yat_main,
                            hipFuncAttributeMaxDynamicSharedMemorySize, SMEM_TOTAL);

  prep_x<<<17424, 256, 0, stream>>>(x, xp, s2p);
  prep_w<<<256, 256, 0, stream>>>(kern, wtb, ksq);
  yat_main<<<512, 512, SMEM_TOTAL, stream>>>(xp, wtb, s2p, ksq, bias, alpha, out);
}